// Round 9
// baseline (1268.859 us; speedup 1.0000x reference)
//
#include <hip/hip_runtime.h>

typedef __attribute__((ext_vector_type(8))) short bf16x8;
typedef __attribute__((ext_vector_type(8))) unsigned short u16x8;
typedef __attribute__((ext_vector_type(16))) float f32x16;

#define SEQ   16
#define NAG   128
#define HD    512
#define NTRAJ 64

__device__ __forceinline__ unsigned short f2bf(float x) {
  unsigned int u = __float_as_uint(x);
  return (unsigned short)((u + 0x7fffu + ((u >> 16) & 1u)) >> 16);  // RNE
}
__device__ __forceinline__ float sigm(float x) { return 1.0f / (1.0f + __expf(-x)); }
__device__ __forceinline__ float tanh_(float x) { return 2.0f / (1.0f + __expf(-2.0f * x)) - 1.0f; }

// Pack weights into 32x32 MFMA-B-fragment order:
//   Wpk[tile*32768 + (ks*64 + lane)*8 + e]
//   col = tile*32 + (lane&31), k = ks*16 + (lane>>5)*8 + e ; tile in [0,64), ks in [0,64)
//   k < 512 -> W_ih[:,k], else W_hh[:,k-512].  bsum[n] = b_ih[n]+b_hh[n].
__global__ void prep_pack32(const float* __restrict__ Wih, const float* __restrict__ Whh,
                            const float* __restrict__ bih, const float* __restrict__ bhh,
                            unsigned short* __restrict__ Wpk, float* __restrict__ bsum) {
  const int t  = blockIdx.x >> 6;
  const int ks = blockIdx.x & 63;
  const int l  = threadIdx.x;
  const int n  = t * 32 + (l & 31);
  const int k  = ks * 16 + (l >> 5) * 8;
  const float* p = (k < 512) ? (Wih + (size_t)n * 512 + k) : (Whh + (size_t)n * 512 + (k - 512));
  float4 w0 = *(const float4*)p;
  float4 w1 = *(const float4*)(p + 4);
  bf16x8 v = {(short)f2bf(w0.x), (short)f2bf(w0.y), (short)f2bf(w0.z), (short)f2bf(w0.w),
              (short)f2bf(w1.x), (short)f2bf(w1.y), (short)f2bf(w1.z), (short)f2bf(w1.w)};
  *(bf16x8*)(Wpk + ((size_t)blockIdx.x * 64 + l) * 8) = v;
  if (ks == 0 && l < 32) bsum[n] = bih[n] + bhh[n];
}

// x_bf16[b][row][512] : k<256 -> h_self[b][row][256+k], else h_inter[b][row][k-256]
__global__ void prep_xbf(const float* __restrict__ h_self, const float* __restrict__ h_inter,
                         unsigned short* __restrict__ xb) {
  const int b   = blockIdx.x;      // 1024
  const int tid = threadIdx.x;     // 256
  const int row = tid >> 1;
  const int half = tid & 1;
  const float* src = half
      ? h_inter + ((size_t)b * NAG + row) * 256 - 256   // index with k directly
      : h_self  + ((size_t)b * NAG + row) * HD + 256;
  unsigned short* dst = xb + ((size_t)b * NAG + row) * 512;
  #pragma unroll
  for (int p = 0; p < 32; ++p) {
    int k = half * 256 + p * 8;
    const float* sp = half ? (src + k) : (src + (k));   // half0: k in [0,256); half1: src-256+k
    float4 v0 = *(const float4*)sp;
    float4 v1 = *(const float4*)(sp + 4);
    u16x8 u = {f2bf(v0.x), f2bf(v0.y), f2bf(v0.z), f2bf(v0.w),
               f2bf(v1.x), f2bf(v1.y), f2bf(v1.z), f2bf(v1.w)};
    *(u16x8*)&dst[k] = u;
  }
}

// ---------------- per-timestep kernel ----------------------------------------
// grid 512 = 128 rowblocks(64 rows) x 4 col-slices. ns=bid&3 constant per XCD.
// Wave: rowgroup rg=w&1 (32 rows), col-tile set ctq=w>>1 (one 32-col tile per gate
// quadrant) -> acc[4] (64 f32), lane-local i/f/g/o.
__global__ __launch_bounds__(512, 1)
void lstm_step(const int t,
               const float* __restrict__ hxs, const float* __restrict__ cxs,
               const int* __restrict__ reset,
               const unsigned short* __restrict__ Wpk, const float* __restrict__ bsum,
               const unsigned short* __restrict__ xb, unsigned short* hping,
               float* out) {
  __shared__ __align__(16) unsigned short A[64 * 1024];  // 128 KB

  const int tid  = threadIdx.x;
  const int w    = tid >> 6;
  const int lane = tid & 63;
  const int c32  = lane & 31;
  const int kh   = lane >> 5;
  const int rg   = w & 1;
  const int ctq  = w >> 1;

  const int bid  = blockIdx.x;
  const int ns   = bid & 3;
  const int rb   = bid >> 2;        // 0..127
  const int traj = rb >> 1;
  const int row0 = (rb & 1) * 64;   // global row base within traj
  const int b    = traj * SEQ + t;
  const int mt   = 1 - reset[b];
  const size_t CYS = (size_t)SEQ * NTRAJ * NAG * HD;  // 67108864

  { // ---- stage A = [x | h(t-1)] bf16, swizzled ----
    const int r    = tid >> 3;        // local row 0..63
    const int k8   = tid & 7;         // k-chunk of 128
    const int grow = row0 + r;        // row within traj 0..127
    const int sw   = (r & 31) << 3;
    if (k8 < 4) {  // x half: k in [0,512)
      const unsigned short* xsrc = xb + ((size_t)b * NAG + grow) * 512;
      #pragma unroll
      for (int p = 0; p < 16; ++p) {
        int k = k8 * 128 + p * 8;
        u16x8 v = *(const u16x8*)&xsrc[k];
        *(u16x8*)&A[r * 1024 + (k ^ sw)] = v;
      }
    } else if (t == 0) {  // h(0) from hxs f32, masked
      const float* hsrc = hxs + ((size_t)b * NAG + grow) * HD;
      #pragma unroll
      for (int p = 0; p < 16; ++p) {
        int k = k8 * 128 + p * 8;
        int hk = k - 512;
        u16x8 u = {0, 0, 0, 0, 0, 0, 0, 0};
        if (mt) {
          float4 v0 = *(const float4*)(hsrc + hk);
          float4 v1 = *(const float4*)(hsrc + hk + 4);
          u = u16x8{f2bf(v0.x), f2bf(v0.y), f2bf(v0.z), f2bf(v0.w),
                    f2bf(v1.x), f2bf(v1.y), f2bf(v1.z), f2bf(v1.w)};
        }
        *(u16x8*)&A[r * 1024 + (k ^ sw)] = u;
      }
    } else {  // h(t-1) from bf16 ping-pong, masked
      const unsigned short* hsrc =
          hping + ((size_t)(((t - 1) & 1) * NTRAJ + traj) * NAG + grow) * 512;
      #pragma unroll
      for (int p = 0; p < 16; ++p) {
        int k = k8 * 128 + p * 8;
        u16x8 u = {0, 0, 0, 0, 0, 0, 0, 0};
        if (mt) u = *(const u16x8*)&hsrc[k - 512];
        *(u16x8*)&A[r * 1024 + (k ^ sw)] = u;
      }
    }
  }

  // bias-initialized accumulators
  const int hd = ns * 128 + ctq * 32 + c32;
  f32x16 acc[4];
  #pragma unroll
  for (int q = 0; q < 4; ++q) {
    float bq = bsum[q * 512 + hd];
    #pragma unroll
    for (int e = 0; e < 16; ++e) acc[q][e] = bq;
  }

  // B-fragment bases: tiles {q*16 + ns*4 + ctq}
  const unsigned short* Wt[4];
  #pragma unroll
  for (int q = 0; q < 4; ++q)
    Wt[q] = Wpk + (size_t)(q * 16 + ns * 4 + ctq) * 32768 + (size_t)lane * 8;

  bf16x8 B0[4], B1[4];
  auto ldB = [&](bf16x8* B, int ks) {
    const int off = ks * 512;
    B[0] = *(const bf16x8*)(Wt[0] + off);
    B[1] = *(const bf16x8*)(Wt[1] + off);
    B[2] = *(const bf16x8*)(Wt[2] + off);
    B[3] = *(const bf16x8*)(Wt[3] + off);
  };
  ldB(B0, 0);
  ldB(B1, 1);

  __syncthreads();

  const int arow = rg * 32 + c32;
  const int asw  = c32 << 3;

  #pragma unroll 1
  for (int kp = 0; kp < 32; ++kp) {
    const int ks0 = kp * 2;
    {
      bf16x8 a = *(const bf16x8*)&A[arow * 1024 + ((ks0 * 16 + kh * 8) ^ asw)];
      __builtin_amdgcn_s_setprio(1);
      acc[0] = __builtin_amdgcn_mfma_f32_32x32x16_bf16(a, B0[0], acc[0], 0, 0, 0);
      acc[1] = __builtin_amdgcn_mfma_f32_32x32x16_bf16(a, B0[1], acc[1], 0, 0, 0);
      acc[2] = __builtin_amdgcn_mfma_f32_32x32x16_bf16(a, B0[2], acc[2], 0, 0, 0);
      acc[3] = __builtin_amdgcn_mfma_f32_32x32x16_bf16(a, B0[3], acc[3], 0, 0, 0);
      __builtin_amdgcn_s_setprio(0);
      ldB(B0, (ks0 + 2 < 64) ? ks0 + 2 : 63);
    }
    {
      bf16x8 a = *(const bf16x8*)&A[arow * 1024 + (((ks0 + 1) * 16 + kh * 8) ^ asw)];
      __builtin_amdgcn_s_setprio(1);
      acc[0] = __builtin_amdgcn_mfma_f32_32x32x16_bf16(a, B1[0], acc[0], 0, 0, 0);
      acc[1] = __builtin_amdgcn_mfma_f32_32x32x16_bf16(a, B1[1], acc[1], 0, 0, 0);
      acc[2] = __builtin_amdgcn_mfma_f32_32x32x16_bf16(a, B1[2], acc[2], 0, 0, 0);
      acc[3] = __builtin_amdgcn_mfma_f32_32x32x16_bf16(a, B1[3], acc[3], 0, 0, 0);
      __builtin_amdgcn_s_setprio(0);
      ldB(B1, (ks0 + 3 < 64) ? ks0 + 3 : 63);
    }
  }

  // epilogue: cell update; lane-local i/f/g/o at same (row, hd)
  unsigned short* hw = hping + ((size_t)((t & 1) * NTRAJ + traj) * NAG) * 512;
  #pragma unroll
  for (int reg = 0; reg < 16; ++reg) {
    const int crow = (reg & 3) + 8 * (reg >> 2) + 4 * kh;
    const int grow = row0 + rg * 32 + crow;
    float cp = (t == 0) ? cxs[((size_t)b * NAG + grow) * HD + hd]
                        : out[CYS + ((size_t)(b - 1) * NAG + grow) * HD + hd];
    cp = mt ? cp : 0.0f;
    float gi = acc[0][reg];
    float gf = acc[1][reg];
    float gg = acc[2][reg];
    float go = acc[3][reg];
    float cn = sigm(gf) * cp + sigm(gi) * tanh_(gg);
    float hn = sigm(go) * tanh_(cn);
    const size_t ob = ((size_t)b * NAG + grow) * HD + hd;
    out[ob] = hn;
    out[CYS + ob] = cn;
    hw[(size_t)grow * 512 + hd] = f2bf(hn);
  }
}

// ---------------- fallback (monolithic, from-global weights, proven-correct) --
__device__ __forceinline__ bf16x8 loadBf(const float* __restrict__ Wih,
                                         const float* __restrict__ Whh,
                                         int tile, int ks, int lane) {
  int n = tile * 32 + (lane & 31);
  int k = ks * 16 + (lane >> 5) * 8;
  const float* p = (k < 512) ? (Wih + (size_t)n * 512 + k) : (Whh + (size_t)n * 512 + (k - 512));
  float4 w0 = *(const float4*)p;
  float4 w1 = *(const float4*)(p + 4);
  return bf16x8{(short)f2bf(w0.x), (short)f2bf(w0.y), (short)f2bf(w0.z), (short)f2bf(w0.w),
                (short)f2bf(w1.x), (short)f2bf(w1.y), (short)f2bf(w1.z), (short)f2bf(w1.w)};
}

__global__ __launch_bounds__(512, 2)
void lstm_fb(const float* __restrict__ hxs, const float* __restrict__ cxs,
             const float* __restrict__ h_self, const float* __restrict__ h_inter,
             const int* __restrict__ reset,
             const float* __restrict__ Wih, const float* __restrict__ Whh,
             const float* __restrict__ bih, const float* __restrict__ bhh,
             float* __restrict__ out) {
  __shared__ __align__(16) unsigned short x_lds[32 * 512];
  __shared__ __align__(16) unsigned short h_lds[2][32 * 512];
  const int tid = threadIdx.x;
  const int w = tid >> 6, lane = tid & 63;
  const int colB = lane & 31, khB = lane >> 5, row = colB;
  const int asw = (row & 7) << 3;
  const int bid = blockIdx.x, traj = bid >> 2, agent0 = (bid & 3) * 32;
  const int rS = tid >> 4, l16 = tid & 15, swS = (rS & 7) << 3;
  const size_t CYS = (size_t)SEQ * NAG * NTRAJ * HD;
  {
    const float* src = hxs + ((size_t)traj * SEQ * NAG + (agent0 + rS)) * HD;
    #pragma unroll
    for (int p = 0; p < 8; ++p) {
      int k = p * 64 + l16 * 4;
      float4 v = *(const float4*)(src + k);
      *(ushort4*)&h_lds[0][rS * 512 + (k ^ swS)] =
          make_ushort4(f2bf(v.x), f2bf(v.y), f2bf(v.z), f2bf(v.w));
    }
  }
  float c_reg[2][16];
  float biasv[2][4];
  {
    #pragma unroll
    for (int u = 0; u < 2; ++u)
      #pragma unroll
      for (int q = 0; q < 4; ++q) {
        int n = q * 512 + w * 64 + u * 32 + colB;
        biasv[u][q] = bih[n] + bhh[n];
      }
    const size_t cbase = ((size_t)traj * SEQ * NAG + agent0) * HD;
    #pragma unroll
    for (int u = 0; u < 2; ++u)
      #pragma unroll
      for (int reg = 0; reg < 16; ++reg) {
        int r = (reg & 3) + 8 * (reg >> 2) + 4 * khB;
        c_reg[u][reg] = cxs[cbase + (size_t)r * HD + w * 64 + u * 32 + colB];
      }
  }
  for (int t = 0; t < SEQ; ++t) {
    const int b = traj * SEQ + t;
    const int mt = 1 - reset[b];
    const unsigned short* hcur = h_lds[t & 1];
    unsigned short* hnxt = h_lds[(t & 1) ^ 1];
    {
      const float* srcs = h_self + ((size_t)b * NAG + (agent0 + rS)) * HD + 256;
      const float* srci = h_inter + ((size_t)b * NAG + (agent0 + rS)) * 256;
      #pragma unroll
      for (int p = 0; p < 8; ++p) {
        int k = p * 64 + l16 * 4;
        const float* sp = (k < 256) ? (srcs + k) : (srci + (k - 256));
        float4 v = *(const float4*)sp;
        *(ushort4*)&x_lds[rS * 512 + (k ^ swS)] =
            make_ushort4(f2bf(v.x), f2bf(v.y), f2bf(v.z), f2bf(v.w));
      }
      if (mt == 0) {
        uint4* pz = (uint4*)h_lds[t & 1];
        #pragma unroll
        for (int i = 0; i < 4; ++i) pz[tid + i * 512] = uint4{0, 0, 0, 0};
      }
    }
    __syncthreads();
    auto lda = [&](int ks, const unsigned short* src) -> bf16x8 {
      int kk = (ks & 31) * 16 + khB * 8;
      return *(const bf16x8*)(src + row * 512 + (kk ^ asw));
    };
    #pragma unroll
    for (int u = 0; u < 2; ++u) {
      const int t0 = w * 2 + u, t1 = 16 + w * 2 + u, t2 = 32 + w * 2 + u, t3 = 48 + w * 2 + u;
      f32x16 acc[4];
      #pragma unroll
      for (int q = 0; q < 4; ++q)
        #pragma unroll
        for (int e = 0; e < 16; ++e) acc[q][e] = biasv[u][q];
      bf16x8 Ba[4], Bb[4];
      auto ldB = [&](bf16x8* B, int ks) {
        B[0] = loadBf(Wih, Whh, t0, ks, lane);
        B[1] = loadBf(Wih, Whh, t1, ks, lane);
        B[2] = loadBf(Wih, Whh, t2, ks, lane);
        B[3] = loadBf(Wih, Whh, t3, ks, lane);
      };
      ldB(Ba, 0);
      ldB(Bb, 1);
      #pragma unroll 1
      for (int kp = 0; kp < 32; ++kp) {
        const int ks0 = kp * 2;
        const unsigned short* ab = (ks0 < 32) ? x_lds : hcur;
        bf16x8 a0 = lda(ks0, ab);
        __builtin_amdgcn_s_setprio(1);
        acc[0] = __builtin_amdgcn_mfma_f32_32x32x16_bf16(a0, Ba[0], acc[0], 0, 0, 0);
        acc[1] = __builtin_amdgcn_mfma_f32_32x32x16_bf16(a0, Ba[1], acc[1], 0, 0, 0);
        acc[2] = __builtin_amdgcn_mfma_f32_32x32x16_bf16(a0, Ba[2], acc[2], 0, 0, 0);
        acc[3] = __builtin_amdgcn_mfma_f32_32x32x16_bf16(a0, Ba[3], acc[3], 0, 0, 0);
        __builtin_amdgcn_s_setprio(0);
        ldB(Ba, (ks0 + 2 < 64) ? ks0 + 2 : 63);
        const unsigned short* ab1 = (ks0 + 1 < 32) ? x_lds : hcur;
        bf16x8 a1 = lda(ks0 + 1, ab1);
        __builtin_amdgcn_s_setprio(1);
        acc[0] = __builtin_amdgcn_mfma_f32_32x32x16_bf16(a1, Bb[0], acc[0], 0, 0, 0);
        acc[1] = __builtin_amdgcn_mfma_f32_32x32x16_bf16(a1, Bb[1], acc[1], 0, 0, 0);
        acc[2] = __builtin_amdgcn_mfma_f32_32x32x16_bf16(a1, Bb[2], acc[2], 0, 0, 0);
        acc[3] = __builtin_amdgcn_mfma_f32_32x32x16_bf16(a1, Bb[3], acc[3], 0, 0, 0);
        __builtin_amdgcn_s_setprio(0);
        ldB(Bb, (ks0 + 3 < 64) ? ks0 + 3 : 63);
      }
      const int hd = w * 64 + u * 32 + colB;
      #pragma unroll
      for (int reg = 0; reg < 16; ++reg) {
        float gi = acc[0][reg], gf = acc[1][reg], gg = acc[2][reg], go = acc[3][reg];
        float cp = mt ? c_reg[u][reg] : 0.0f;
        float cn = sigm(gf) * cp + sigm(gi) * tanh_(gg);
        float hn = sigm(go) * tanh_(cn);
        c_reg[u][reg] = cn;
        int r = (reg & 3) + 8 * (reg >> 2) + 4 * khB;
        size_t ob = ((size_t)b * NAG + agent0 + r) * HD + hd;
        out[ob] = hn;
        out[CYS + ob] = cn;
        hnxt[r * 512 + (hd ^ ((r & 7) << 3))] = f2bf(hn);
      }
    }
    __syncthreads();
  }
}

extern "C" void kernel_launch(void* const* d_in, const int* in_sizes, int n_in,
                              void* d_out, int out_size, void* d_ws, size_t ws_size,
                              hipStream_t stream) {
  (void)in_sizes; (void)n_in; (void)out_size;
  const float* hxs     = (const float*)d_in[1];
  const float* cxs     = (const float*)d_in[2];
  const float* h_self  = (const float*)d_in[3];
  const float* h_inter = (const float*)d_in[4];
  const int*   reset   = (const int*)d_in[5];
  const float* Wih     = (const float*)d_in[6];
  const float* Whh     = (const float*)d_in[7];
  const float* bih     = (const float*)d_in[8];
  const float* bhh     = (const float*)d_in[9];
  float* out = (float*)d_out;

  const size_t WPK_SZ  = (size_t)2048 * 1024 * 2;                 // 4 MB
  const size_t BSUM_SZ = 8192;
  const size_t XB_SZ   = (size_t)1024 * NAG * 512 * 2;            // 134.2 MB
  const size_t HP_SZ   = (size_t)2 * NTRAJ * NAG * 512 * 2;       // 16.8 MB
  const size_t need    = WPK_SZ + BSUM_SZ + XB_SZ + HP_SZ;

  if (d_ws != nullptr && ws_size >= need) {
    char* base = (char*)d_ws;
    unsigned short* Wpk   = (unsigned short*)base;
    float*          bsum  = (float*)(base + WPK_SZ);
    unsigned short* xb    = (unsigned short*)(base + WPK_SZ + BSUM_SZ);
    unsigned short* hping = (unsigned short*)(base + WPK_SZ + BSUM_SZ + XB_SZ);
    prep_pack32<<<4096, 64, 0, stream>>>(Wih, Whh, bih, bhh, Wpk, bsum);
    prep_xbf<<<1024, 256, 0, stream>>>(h_self, h_inter, xb);
    for (int t = 0; t < SEQ; ++t)
      lstm_step<<<512, 512, 0, stream>>>(t, hxs, cxs, reset, Wpk, bsum, xb, hping, out);
  } else {
    lstm_fb<<<256, 512, 0, stream>>>(hxs, cxs, h_self, h_inter, reset,
                                     Wih, Whh, bih, bhh, out);
  }
}

// Round 10
// 1144.047 us; speedup vs baseline: 1.1091x; 1.1091x over previous
//
#include <hip/hip_runtime.h>

typedef __attribute__((ext_vector_type(8))) short bf16x8;
typedef __attribute__((ext_vector_type(8))) unsigned short u16x8;
typedef __attribute__((ext_vector_type(16))) float f32x16;

#define SEQ   16
#define NAG   128
#define HD    512
#define NTRAJ 64

__device__ __forceinline__ unsigned short f2bf(float x) {
  unsigned int u = __float_as_uint(x);
  return (unsigned short)((u + 0x7fffu + ((u >> 16) & 1u)) >> 16);  // RNE
}
__device__ __forceinline__ float sigm(float x) { return 1.0f / (1.0f + __expf(-x)); }
__device__ __forceinline__ float tanh_(float x) { return 2.0f / (1.0f + __expf(-2.0f * x)) - 1.0f; }

// Pack weights into 32x32 MFMA-B-fragment order (proven R5-R7):
//   Wpk[tile*32768 + (ks*64 + lane)*8 + e]
//   col = tile*32 + (lane&31), k = ks*16 + (lane>>5)*8 + e ; tile,ks in [0,64)
//   k < 512 -> W_ih[:,k], else W_hh[:,k-512].  bsum[n] = b_ih[n]+b_hh[n].
__global__ void prep_pack32(const float* __restrict__ Wih, const float* __restrict__ Whh,
                            const float* __restrict__ bih, const float* __restrict__ bhh,
                            unsigned short* __restrict__ Wpk, float* __restrict__ bsum) {
  const int t  = blockIdx.x >> 6;
  const int ks = blockIdx.x & 63;
  const int l  = threadIdx.x;
  const int n  = t * 32 + (l & 31);
  const int k  = ks * 16 + (l >> 5) * 8;
  const float* p = (k < 512) ? (Wih + (size_t)n * 512 + k) : (Whh + (size_t)n * 512 + (k - 512));
  float4 w0 = *(const float4*)p;
  float4 w1 = *(const float4*)(p + 4);
  bf16x8 v = {(short)f2bf(w0.x), (short)f2bf(w0.y), (short)f2bf(w0.z), (short)f2bf(w0.w),
              (short)f2bf(w1.x), (short)f2bf(w1.y), (short)f2bf(w1.z), (short)f2bf(w1.w)};
  *(bf16x8*)(Wpk + ((size_t)blockIdx.x * 64 + l) * 8) = v;
  if (ks == 0 && l < 32) bsum[n] = bih[n] + bhh[n];
}

// x_bf16[b][row][512] : k<256 -> h_self[b][row][256+k], else h_inter[b][row][k-256]
__global__ void prep_xbf(const float* __restrict__ h_self, const float* __restrict__ h_inter,
                         unsigned short* __restrict__ xb) {
  const int b   = blockIdx.x;      // 1024
  const int tid = threadIdx.x;     // 256
  const int row = tid >> 1;
  const int half = tid & 1;
  const float* src = half
      ? h_inter + ((size_t)b * NAG + row) * 256 - 256
      : h_self  + ((size_t)b * NAG + row) * HD + 256;
  unsigned short* dst = xb + ((size_t)b * NAG + row) * 512;
  #pragma unroll
  for (int p = 0; p < 32; ++p) {
    int k = half * 256 + p * 8;
    const float* sp = src + k;
    float4 v0 = *(const float4*)sp;
    float4 v1 = *(const float4*)(sp + 4);
    u16x8 u = {f2bf(v0.x), f2bf(v0.y), f2bf(v0.z), f2bf(v0.w),
               f2bf(v1.x), f2bf(v1.y), f2bf(v1.z), f2bf(v1.w)};
    *(u16x8*)&dst[k] = u;
  }
}

// ---------------- per-timestep kernel, BM=128 x 512 cols, M_rep=2 ------------
// grid 256 = 64 traj x 4 hd-slices (ns = bid&3 constant per XCD -> 1MB weights
// L2-resident). 8 waves = 2 rowgroups(64) x 4 colgroups(128). Wave: 2 row-tiles
// (32 rows) x 4 gate-quadrant col-tiles(32) -> acc[2][4] f32x16 = 128 AGPR,
// lane-local i/f/g/o. A staged in 4 K-quarter phases, dbuf 2x64KB, async-split.
__global__ __launch_bounds__(512)
void lstm_step(const int t,
               const float* __restrict__ hxs, const float* __restrict__ cxs,
               const int* __restrict__ reset,
               const unsigned short* __restrict__ Wpk, const float* __restrict__ bsum,
               const unsigned short* __restrict__ xb, unsigned short* hping,
               float* out) {
  __shared__ __align__(16) unsigned short A[2][128 * 256];  // 2 x 64 KB

  const int tid  = threadIdx.x;
  const int w    = tid >> 6;
  const int lane = tid & 63;
  const int c32  = lane & 31;
  const int kh   = lane >> 5;
  const int rg   = w >> 2;      // rowgroup (64 rows)
  const int cg   = w & 3;       // colgroup (128 cols)

  const int bid  = blockIdx.x;
  const int ns   = bid & 3;
  const int traj = bid >> 2;
  const int b    = traj * SEQ + t;
  const int mt   = 1 - reset[b];
  const size_t CYS = (size_t)SEQ * NTRAJ * NAG * HD;  // 67108864

  // staging mapping: 512 threads -> 128 rows x 4 k16-chunks (64 k each)
  const int rS = tid >> 2;
  const int kq = tid & 3;
  const int swS = (rS & 31) << 3;

  u16x8 sreg[8];
  auto stage_load = [&](int ph) {  // load K-quarter [ph*256,(ph+1)*256) to regs
    if (ph < 2) {
      const unsigned short* src = xb + ((size_t)b * NAG + rS) * 512 + ph * 256 + kq * 64;
      #pragma unroll
      for (int p = 0; p < 8; ++p) sreg[p] = *(const u16x8*)&src[p * 8];
    } else if (t == 0) {
      const float* hsrc = hxs + ((size_t)b * NAG + rS) * HD + (ph - 2) * 256 + kq * 64;
      #pragma unroll
      for (int p = 0; p < 8; ++p) {
        u16x8 u = {0, 0, 0, 0, 0, 0, 0, 0};
        if (mt) {
          float4 v0 = *(const float4*)(hsrc + p * 8);
          float4 v1 = *(const float4*)(hsrc + p * 8 + 4);
          u = u16x8{f2bf(v0.x), f2bf(v0.y), f2bf(v0.z), f2bf(v0.w),
                    f2bf(v1.x), f2bf(v1.y), f2bf(v1.z), f2bf(v1.w)};
        }
        sreg[p] = u;
      }
    } else {
      const unsigned short* hsrc =
          hping + ((size_t)(((t - 1) & 1) * NTRAJ + traj) * NAG + rS) * 512 + (ph - 2) * 256 + kq * 64;
      #pragma unroll
      for (int p = 0; p < 8; ++p) {
        u16x8 u = {0, 0, 0, 0, 0, 0, 0, 0};
        if (mt) u = *(const u16x8*)&hsrc[p * 8];
        sreg[p] = u;
      }
    }
  };
  auto stage_write = [&](int ph) {
    unsigned short* dst = &A[ph & 1][rS * 256];
    #pragma unroll
    for (int p = 0; p < 8; ++p) {
      int k = kq * 64 + p * 8;
      *(u16x8*)&dst[k ^ swS] = sreg[p];
    }
  };

  // bias-initialized accumulators (AGPR)
  const int hd = ns * 128 + cg * 32 + c32;
  f32x16 acc[2][4];
  #pragma unroll
  for (int q = 0; q < 4; ++q) {
    float bq = bsum[q * 512 + hd];
    #pragma unroll
    for (int rt = 0; rt < 2; ++rt)
      #pragma unroll
      for (int e = 0; e < 16; ++e) acc[rt][q][e] = bq;
  }

  // B-fragment bases: tiles {q*16 + ns*4 + cg} -> cols q*512 + ns*128 + cg*32 +[0,32)
  const unsigned short* Wt0 = Wpk + (size_t)(0 * 16 + ns * 4 + cg) * 32768 + (size_t)lane * 8;
  const unsigned short* Wt1 = Wpk + (size_t)(1 * 16 + ns * 4 + cg) * 32768 + (size_t)lane * 8;
  const unsigned short* Wt2 = Wpk + (size_t)(2 * 16 + ns * 4 + cg) * 32768 + (size_t)lane * 8;
  const unsigned short* Wt3 = Wpk + (size_t)(3 * 16 + ns * 4 + cg) * 32768 + (size_t)lane * 8;

  bf16x8 B0[4], B1[4];
  auto ldB = [&](bf16x8* B, int ks) {  // global ks in [0,64)
    const int off = ks * 512;
    B[0] = *(const bf16x8*)(Wt0 + off);
    B[1] = *(const bf16x8*)(Wt1 + off);
    B[2] = *(const bf16x8*)(Wt2 + off);
    B[3] = *(const bf16x8*)(Wt3 + off);
  };
  ldB(B0, 0);
  ldB(B1, 1);

  // prologue: stage phase 0
  stage_load(0);
  stage_write(0);
  __syncthreads();

  const int arow0 = rg * 64 + c32;
  const int arow1 = rg * 64 + 32 + c32;
  const int asw   = c32 << 3;   // (arow&31)<<3 is identical for both rows

  #pragma unroll 1
  for (int ph = 0; ph < 4; ++ph) {
    if (ph < 3) stage_load(ph + 1);           // issue next-quarter loads early
    const unsigned short* ab = A[ph & 1];
    #pragma unroll 1
    for (int k2 = 0; k2 < 8; ++k2) {
      const int lk0 = k2 * 2;                  // local ks in [0,16)
      {
        const int kk = (lk0 * 16 + kh * 8) ^ asw;
        bf16x8 a0 = *(const bf16x8*)&ab[arow0 * 256 + kk];
        bf16x8 a1 = *(const bf16x8*)&ab[arow1 * 256 + kk];
        __builtin_amdgcn_s_setprio(1);
        acc[0][0] = __builtin_amdgcn_mfma_f32_32x32x16_bf16(a0, B0[0], acc[0][0], 0, 0, 0);
        acc[0][1] = __builtin_amdgcn_mfma_f32_32x32x16_bf16(a0, B0[1], acc[0][1], 0, 0, 0);
        acc[0][2] = __builtin_amdgcn_mfma_f32_32x32x16_bf16(a0, B0[2], acc[0][2], 0, 0, 0);
        acc[0][3] = __builtin_amdgcn_mfma_f32_32x32x16_bf16(a0, B0[3], acc[0][3], 0, 0, 0);
        acc[1][0] = __builtin_amdgcn_mfma_f32_32x32x16_bf16(a1, B0[0], acc[1][0], 0, 0, 0);
        acc[1][1] = __builtin_amdgcn_mfma_f32_32x32x16_bf16(a1, B0[1], acc[1][1], 0, 0, 0);
        acc[1][2] = __builtin_amdgcn_mfma_f32_32x32x16_bf16(a1, B0[2], acc[1][2], 0, 0, 0);
        acc[1][3] = __builtin_amdgcn_mfma_f32_32x32x16_bf16(a1, B0[3], acc[1][3], 0, 0, 0);
        __builtin_amdgcn_s_setprio(0);
        int kf = ph * 16 + lk0 + 2;
        ldB(B0, kf < 64 ? kf : 63);
      }
      {
        const int kk = ((lk0 + 1) * 16 + kh * 8) ^ asw;
        bf16x8 a0 = *(const bf16x8*)&ab[arow0 * 256 + kk];
        bf16x8 a1 = *(const bf16x8*)&ab[arow1 * 256 + kk];
        __builtin_amdgcn_s_setprio(1);
        acc[0][0] = __builtin_amdgcn_mfma_f32_32x32x16_bf16(a0, B1[0], acc[0][0], 0, 0, 0);
        acc[0][1] = __builtin_amdgcn_mfma_f32_32x32x16_bf16(a0, B1[1], acc[0][1], 0, 0, 0);
        acc[0][2] = __builtin_amdgcn_mfma_f32_32x32x16_bf16(a0, B1[2], acc[0][2], 0, 0, 0);
        acc[0][3] = __builtin_amdgcn_mfma_f32_32x32x16_bf16(a0, B1[3], acc[0][3], 0, 0, 0);
        acc[1][0] = __builtin_amdgcn_mfma_f32_32x32x16_bf16(a1, B1[0], acc[1][0], 0, 0, 0);
        acc[1][1] = __builtin_amdgcn_mfma_f32_32x32x16_bf16(a1, B1[1], acc[1][1], 0, 0, 0);
        acc[1][2] = __builtin_amdgcn_mfma_f32_32x32x16_bf16(a1, B1[2], acc[1][2], 0, 0, 0);
        acc[1][3] = __builtin_amdgcn_mfma_f32_32x32x16_bf16(a1, B1[3], acc[1][3], 0, 0, 0);
        __builtin_amdgcn_s_setprio(0);
        int kf = ph * 16 + lk0 + 3;
        ldB(B1, kf < 64 ? kf : 63);
      }
    }
    if (ph < 3) {
      __syncthreads();           // phase ph fully consumed by all waves
      stage_write(ph + 1);       // write next quarter into the other buffer
      __syncthreads();
    }
  }

  // epilogue: cell update; lane-local i/f/g/o at same (row, hd)
  unsigned short* hw = hping + ((size_t)((t & 1) * NTRAJ + traj) * NAG) * 512;
  #pragma unroll
  for (int rt = 0; rt < 2; ++rt) {
    #pragma unroll
    for (int reg = 0; reg < 16; ++reg) {
      const int crow = (reg & 3) + 8 * (reg >> 2) + 4 * kh;
      const int grow = rg * 64 + rt * 32 + crow;
      float cp = (t == 0) ? cxs[((size_t)b * NAG + grow) * HD + hd]
                          : out[CYS + ((size_t)(b - 1) * NAG + grow) * HD + hd];
      cp = mt ? cp : 0.0f;
      float gi = acc[rt][0][reg];
      float gf = acc[rt][1][reg];
      float gg = acc[rt][2][reg];
      float go = acc[rt][3][reg];
      float cn = sigm(gf) * cp + sigm(gi) * tanh_(gg);
      float hn = sigm(go) * tanh_(cn);
      const size_t ob = ((size_t)b * NAG + grow) * HD + hd;
      out[ob] = hn;
      out[CYS + ob] = cn;
      hw[(size_t)grow * 512 + hd] = f2bf(hn);
    }
  }
}

// ---------------- fallback (monolithic, from-global weights, proven) ---------
__device__ __forceinline__ bf16x8 loadBf(const float* __restrict__ Wih,
                                         const float* __restrict__ Whh,
                                         int tile, int ks, int lane) {
  int n = tile * 32 + (lane & 31);
  int k = ks * 16 + (lane >> 5) * 8;
  const float* p = (k < 512) ? (Wih + (size_t)n * 512 + k) : (Whh + (size_t)n * 512 + (k - 512));
  float4 w0 = *(const float4*)p;
  float4 w1 = *(const float4*)(p + 4);
  return bf16x8{(short)f2bf(w0.x), (short)f2bf(w0.y), (short)f2bf(w0.z), (short)f2bf(w0.w),
                (short)f2bf(w1.x), (short)f2bf(w1.y), (short)f2bf(w1.z), (short)f2bf(w1.w)};
}

__global__ __launch_bounds__(512, 2)
void lstm_fb(const float* __restrict__ hxs, const float* __restrict__ cxs,
             const float* __restrict__ h_self, const float* __restrict__ h_inter,
             const int* __restrict__ reset,
             const float* __restrict__ Wih, const float* __restrict__ Whh,
             const float* __restrict__ bih, const float* __restrict__ bhh,
             float* __restrict__ out) {
  __shared__ __align__(16) unsigned short x_lds[32 * 512];
  __shared__ __align__(16) unsigned short h_lds[2][32 * 512];
  const int tid = threadIdx.x;
  const int w = tid >> 6, lane = tid & 63;
  const int colB = lane & 31, khB = lane >> 5, row = colB;
  const int asw = (row & 7) << 3;
  const int bid = blockIdx.x, traj = bid >> 2, agent0 = (bid & 3) * 32;
  const int rS = tid >> 4, l16 = tid & 15, swS = (rS & 7) << 3;
  const size_t CYS = (size_t)SEQ * NAG * NTRAJ * HD;
  {
    const float* src = hxs + ((size_t)traj * SEQ * NAG + (agent0 + rS)) * HD;
    #pragma unroll
    for (int p = 0; p < 8; ++p) {
      int k = p * 64 + l16 * 4;
      float4 v = *(const float4*)(src + k);
      *(ushort4*)&h_lds[0][rS * 512 + (k ^ swS)] =
          make_ushort4(f2bf(v.x), f2bf(v.y), f2bf(v.z), f2bf(v.w));
    }
  }
  float c_reg[2][16];
  float biasv[2][4];
  {
    #pragma unroll
    for (int u = 0; u < 2; ++u)
      #pragma unroll
      for (int q = 0; q < 4; ++q) {
        int n = q * 512 + w * 64 + u * 32 + colB;
        biasv[u][q] = bih[n] + bhh[n];
      }
    const size_t cbase = ((size_t)traj * SEQ * NAG + agent0) * HD;
    #pragma unroll
    for (int u = 0; u < 2; ++u)
      #pragma unroll
      for (int reg = 0; reg < 16; ++reg) {
        int r = (reg & 3) + 8 * (reg >> 2) + 4 * khB;
        c_reg[u][reg] = cxs[cbase + (size_t)r * HD + w * 64 + u * 32 + colB];
      }
  }
  for (int t = 0; t < SEQ; ++t) {
    const int b = traj * SEQ + t;
    const int mt = 1 - reset[b];
    const unsigned short* hcur = h_lds[t & 1];
    unsigned short* hnxt = h_lds[(t & 1) ^ 1];
    {
      const float* srcs = h_self + ((size_t)b * NAG + (agent0 + rS)) * HD + 256;
      const float* srci = h_inter + ((size_t)b * NAG + (agent0 + rS)) * 256;
      #pragma unroll
      for (int p = 0; p < 8; ++p) {
        int k = p * 64 + l16 * 4;
        const float* sp = (k < 256) ? (srcs + k) : (srci + (k - 256));
        float4 v = *(const float4*)sp;
        *(ushort4*)&x_lds[rS * 512 + (k ^ swS)] =
            make_ushort4(f2bf(v.x), f2bf(v.y), f2bf(v.z), f2bf(v.w));
      }
      if (mt == 0) {
        uint4* pz = (uint4*)h_lds[t & 1];
        #pragma unroll
        for (int i = 0; i < 4; ++i) pz[tid + i * 512] = uint4{0, 0, 0, 0};
      }
    }
    __syncthreads();
    auto lda = [&](int ks, const unsigned short* src) -> bf16x8 {
      int kk = (ks & 31) * 16 + khB * 8;
      return *(const bf16x8*)(src + row * 512 + (kk ^ asw));
    };
    #pragma unroll
    for (int u = 0; u < 2; ++u) {
      const int t0 = w * 2 + u, t1 = 16 + w * 2 + u, t2 = 32 + w * 2 + u, t3 = 48 + w * 2 + u;
      f32x16 acc[4];
      #pragma unroll
      for (int q = 0; q < 4; ++q)
        #pragma unroll
        for (int e = 0; e < 16; ++e) acc[q][e] = biasv[u][q];
      bf16x8 Ba[4], Bb[4];
      auto ldB = [&](bf16x8* B, int ks) {
        B[0] = loadBf(Wih, Whh, t0, ks, lane);
        B[1] = loadBf(Wih, Whh, t1, ks, lane);
        B[2] = loadBf(Wih, Whh, t2, ks, lane);
        B[3] = loadBf(Wih, Whh, t3, ks, lane);
      };
      ldB(Ba, 0);
      ldB(Bb, 1);
      #pragma unroll 1
      for (int kp = 0; kp < 32; ++kp) {
        const int ks0 = kp * 2;
        const unsigned short* ab = (ks0 < 32) ? x_lds : hcur;
        bf16x8 a0 = lda(ks0, ab);
        __builtin_amdgcn_s_setprio(1);
        acc[0] = __builtin_amdgcn_mfma_f32_32x32x16_bf16(a0, Ba[0], acc[0], 0, 0, 0);
        acc[1] = __builtin_amdgcn_mfma_f32_32x32x16_bf16(a0, Ba[1], acc[1], 0, 0, 0);
        acc[2] = __builtin_amdgcn_mfma_f32_32x32x16_bf16(a0, Ba[2], acc[2], 0, 0, 0);
        acc[3] = __builtin_amdgcn_mfma_f32_32x32x16_bf16(a0, Ba[3], acc[3], 0, 0, 0);
        __builtin_amdgcn_s_setprio(0);
        ldB(Ba, (ks0 + 2 < 64) ? ks0 + 2 : 63);
        const unsigned short* ab1 = (ks0 + 1 < 32) ? x_lds : hcur;
        bf16x8 a1 = lda(ks0 + 1, ab1);
        __builtin_amdgcn_s_setprio(1);
        acc[0] = __builtin_amdgcn_mfma_f32_32x32x16_bf16(a1, Bb[0], acc[0], 0, 0, 0);
        acc[1] = __builtin_amdgcn_mfma_f32_32x32x16_bf16(a1, Bb[1], acc[1], 0, 0, 0);
        acc[2] = __builtin_amdgcn_mfma_f32_32x32x16_bf16(a1, Bb[2], acc[2], 0, 0, 0);
        acc[3] = __builtin_amdgcn_mfma_f32_32x32x16_bf16(a1, Bb[3], acc[3], 0, 0, 0);
        __builtin_amdgcn_s_setprio(0);
        ldB(Bb, (ks0 + 3 < 64) ? ks0 + 3 : 63);
      }
      const int hd = w * 64 + u * 32 + colB;
      #pragma unroll
      for (int reg = 0; reg < 16; ++reg) {
        float gi = acc[0][reg], gf = acc[1][reg], gg = acc[2][reg], go = acc[3][reg];
        float cp = mt ? c_reg[u][reg] : 0.0f;
        float cn = sigm(gf) * cp + sigm(gi) * tanh_(gg);
        float hn = sigm(go) * tanh_(cn);
        c_reg[u][reg] = cn;
        int r = (reg & 3) + 8 * (reg >> 2) + 4 * khB;
        size_t ob = ((size_t)b * NAG + agent0 + r) * HD + hd;
        out[ob] = hn;
        out[CYS + ob] = cn;
        hnxt[r * 512 + (hd ^ ((r & 7) << 3))] = f2bf(hn);
      }
    }
    __syncthreads();
  }
}

extern "C" void kernel_launch(void* const* d_in, const int* in_sizes, int n_in,
                              void* d_out, int out_size, void* d_ws, size_t ws_size,
                              hipStream_t stream) {
  (void)in_sizes; (void)n_in; (void)out_size;
  const float* hxs     = (const float*)d_in[1];
  const float* cxs     = (const float*)d_in[2];
  const float* h_self  = (const float*)d_in[3];
  const float* h_inter = (const float*)d_in[4];
  const int*   reset   = (const int*)d_in[5];
  const float* Wih     = (const float*)d_in[6];
  const float* Whh     = (const float*)d_in[7];
  const float* bih     = (const float*)d_in[8];
  const float* bhh     = (const float*)d_in[9];
  float* out = (float*)d_out;

  const size_t WPK_SZ  = (size_t)2048 * 1024 * 2;                 // 4 MB
  const size_t BSUM_SZ = 8192;
  const size_t XB_SZ   = (size_t)1024 * NAG * 512 * 2;            // 134.2 MB
  const size_t HP_SZ   = (size_t)2 * NTRAJ * NAG * 512 * 2;       // 16.8 MB
  const size_t need    = WPK_SZ + BSUM_SZ + XB_SZ + HP_SZ;

  if (d_ws != nullptr && ws_size >= need) {
    char* base = (char*)d_ws;
    unsigned short* Wpk   = (unsigned short*)base;
    float*          bsum  = (float*)(base + WPK_SZ);
    unsigned short* xb    = (unsigned short*)(base + WPK_SZ + BSUM_SZ);
    unsigned short* hping = (unsigned short*)(base + WPK_SZ + BSUM_SZ + XB_SZ);
    prep_pack32<<<4096, 64, 0, stream>>>(Wih, Whh, bih, bhh, Wpk, bsum);
    prep_xbf<<<1024, 256, 0, stream>>>(h_self, h_inter, xb);
    for (int t = 0; t < SEQ; ++t)
      lstm_step<<<256, 512, 0, stream>>>(t, hxs, cxs, reset, Wpk, bsum, xb, hping, out);
  } else {
    lstm_fb<<<256, 512, 0, stream>>>(hxs, cxs, h_self, h_inter, reset,
                                     Wih, Whh, bih, bhh, out);
  }
}